// Round 10
// baseline (193.292 us; speedup 1.0000x reference)
//
#include <hip/hip_runtime.h>
#include <math.h>

#define HID 128
#define CAP 12288                // padded edges per 256-node bucket
#define NBUCK_MAX 256
#define EPB 8192                 // edges per partA block

typedef _Float16 h2v __attribute__((ext_vector_type(2)));
typedef _Float16 h8v __attribute__((ext_vector_type(8)));
typedef float f4v __attribute__((ext_vector_type(4)));

static inline int ceil_div(int a, int b) { return (a + b - 1) / b; }

// ---------------- setup: transpose weights to fp16, init mask/bcur ----------------

__global__ __launch_bounds__(256) void k_setup(const float* __restrict__ W1, const float* __restrict__ W2,
                                               const float* __restrict__ Wl, _Float16* T1, _Float16* T2,
                                               _Float16* Tl, unsigned int* mask, int* bcur, int mw, int NB) {
    int b = blockIdx.x;
    if (b < 192) {
        int which = b >> 6;
        int idx = (b & 63) * 256 + threadIdx.x;
        int k = idx >> 7, c = idx & 127;
        const float* S = (which == 0) ? W1 : ((which == 1) ? W2 : Wl);
        _Float16* D = (which == 0) ? T1 : ((which == 1) ? T2 : Tl);
        D[c * 128 + k] = (_Float16)S[idx];
    } else {
        int i = (b - 192) * 256 + threadIdx.x;
        if (i < mw) mask[i] = 0u;
        if (i < NB) bcur[i] = i * CAP;
    }
}

// ---------------- bucket partition with block-local counting sort + burst copy-out ----------------

__global__ __launch_bounds__(1024) void k_partA(const int* __restrict__ ei, int* __restrict__ bcur,
                                                unsigned int* __restrict__ ebuf,
                                                const int* __restrict__ batch, unsigned int* mask,
                                                int E, int B, int NB, int NBLKE) {
    if ((int)blockIdx.x >= NBLKE) {
        int i = ((int)blockIdx.x - NBLKE) * 1024 + threadIdx.x;
        if (i < B) { int nd = batch[i]; atomicOr(&mask[nd >> 5], 1u << (nd & 31)); }
        return;
    }
    __shared__ int lcnt[NBUCK_MAX];
    __shared__ int sc[NBUCK_MAX];
    __shared__ int lcur[NBUCK_MAX];
    __shared__ int gbase[NBUCK_MAX];
    __shared__ unsigned int se[EPB];
    int tid = threadIdx.x;
    if (tid < NBUCK_MAX) lcnt[tid] = 0;
    __syncthreads();
    int base = blockIdx.x * EPB;
    unsigned int pk[8];
    int bk[8];
#pragma unroll
    for (int j = 0; j < 8; ++j) {
        int e = base + tid + j * 1024;
        if (e < E) {
            int s = ei[e], d = ei[E + e];
            pk[j] = ((unsigned int)s << 8) | (unsigned int)(d & 255);
            bk[j] = d >> 8;
            atomicAdd(&lcnt[bk[j]], 1);
        } else bk[j] = -1;
    }
    __syncthreads();
    if (tid < NBUCK_MAX) sc[tid] = lcnt[tid];
    __syncthreads();
    for (int off = 1; off < NBUCK_MAX; off <<= 1) {
        int v = 0;
        if (tid < NBUCK_MAX && tid >= off) v = sc[tid - off];
        __syncthreads();
        if (tid < NBUCK_MAX) sc[tid] += v;
        __syncthreads();
    }
    if (tid < NBUCK_MAX) {
        int cc = lcnt[tid];
        int lo = sc[tid] - cc;
        lcur[tid] = lo;
        gbase[tid] = cc ? atomicAdd(&bcur[tid], cc) : 0;
    }
    __syncthreads();
#pragma unroll
    for (int j = 0; j < 8; ++j) {
        if (bk[j] >= 0) {
            int r = atomicAdd(&lcur[bk[j]], 1);
            se[r] = pk[j];
        }
    }
    __syncthreads();
    int wid = tid >> 6, lane = tid & 63;
    for (int b = wid; b < NB; b += 16) {
        int cc = lcnt[b];
        int lo = sc[b] - cc;
        int go = gbase[b];
        for (int i = lane; i < cc; i += 64) ebuf[go + i] = se[lo + i];
    }
}

// ---------------- one-pass CSR (pad to x8) + fused xs cast + zero pad rows ----------------

__global__ __launch_bounds__(256) void k_csr(const unsigned int* __restrict__ ebuf, const int* __restrict__ bcur,
                                             const unsigned int* __restrict__ mask, const float* __restrict__ x,
                                             float* __restrict__ sdinv, int* __restrict__ rs,
                                             int* __restrict__ degpk, unsigned int* __restrict__ csr,
                                             _Float16* __restrict__ xs, _Float16* __restrict__ H, int N) {
    __shared__ unsigned int se[CAP];
    __shared__ int deg[256];
    __shared__ int fde[256];
    __shared__ int sc[256];
    __shared__ int cu[256];
    __shared__ int cf[256];
    __shared__ float sda[256];
    int b = blockIdx.x, t = threadIdx.x;
    deg[t] = 0; fde[t] = 0;
    __syncthreads();
    int base = b * CAP;
    int ecnt = bcur[b] - base;
    for (int i = t; i < ecnt; i += 256) {
        unsigned int v = ebuf[base + i];
        int s = v >> 8;
        int fl = (mask[s >> 5] >> (s & 31)) & 1;
        se[i] = ((unsigned int)s << 9) | ((unsigned int)fl << 8) | (v & 255);
        atomicAdd(&deg[v & 255], 1);
        if (fl) atomicAdd(&fde[v & 255], 1);
    }
    __syncthreads();
    int dv = deg[t], fv = fde[t];
    int pv = (dv + 7) & ~7;
    sc[t] = pv;
    __syncthreads();
    for (int off = 1; off < 256; off <<= 1) {
        int v2 = (t >= off) ? sc[t - off] : 0;
        __syncthreads();
        sc[t] += v2;
        __syncthreads();
    }
    int r0 = base + sc[t] - pv;
    cu[t] = r0;
    cf[t] = r0 + (dv - fv);
    int node = b * 256 + t;
    float da = 0.f;
    if (node < N) {
        rs[node] = r0;
        degpk[node] = dv | (fv << 16);
        float di = rsqrtf((float)(dv + 1));
        da = di;
        if ((mask[node >> 5] >> (node & 31)) & 1) di = -di;
        sdinv[node] = di;
    }
    sda[t] = da;
    __syncthreads();
    for (int i = t; i < ecnt; i += 256) {
        unsigned int v = se[i];
        int d8 = v & 255;
        int p = ((v >> 8) & 1) ? atomicAdd(&cf[d8], 1) : atomicAdd(&cu[d8], 1);
        csr[p] = v >> 9;
    }
    if (node < N) {
        for (int j = dv; j < pv; ++j) csr[r0 + j] = (unsigned int)N;
    }
    int nl0 = b * 256;
    int nmax = min(256, N - nl0);
    for (int idx = t; idx < nmax * 16; idx += 256) {
        int nl = idx >> 4, chunk = idx & 15;
        float dda = sda[nl];
        size_t o = (size_t)(nl0 + nl) * HID + chunk * 8;
        float4 a = *(const float4*)&x[o];
        float4 bb = *(const float4*)&x[o + 4];
        h8v v;
        v[0] = (_Float16)(a.x * dda); v[1] = (_Float16)(a.y * dda);
        v[2] = (_Float16)(a.z * dda); v[3] = (_Float16)(a.w * dda);
        v[4] = (_Float16)(bb.x * dda); v[5] = (_Float16)(bb.y * dda);
        v[6] = (_Float16)(bb.z * dda); v[7] = (_Float16)(bb.w * dda);
        *(h8v*)&xs[o] = v;
    }
    if (b == 0) {
        if (t < 16) *(h8v*)&xs[(size_t)N * HID + t * 8] = (h8v){};
        else if (t < 48) *(h8v*)&H[(size_t)2 * N * HID + (t - 16) * 8] = (h8v){};
    }
}

// ---------------- fused layer 1 (low-LDS): SpMM + MFMA (W1T from global) + relu/bias/dinv -> H ----------------
// LDS = one 16.9 KB buffer shared by sAgg (spmm->MFMA) then sC (epilogue) + bias/da.

__global__ __launch_bounds__(256) void k_layer1(const _Float16* __restrict__ xs, const int* __restrict__ rs,
                                                const int* __restrict__ degpk, const unsigned int* __restrict__ csr,
                                                const float* __restrict__ sdinv, const _Float16* __restrict__ W1T,
                                                const float* __restrict__ bias, _Float16* __restrict__ H, int N) {
    __shared__ __align__(16) char smem[32 * 132 * 4];    // 16.9 KB: sAgg (8.7 KB) then sC
    __shared__ float sbias[128];
    __shared__ float sda[16];
    _Float16* sAgg = (_Float16*)smem;                     // [32][136] halves
    float* sC = (float*)smem;                             // [32][132] floats

    int tid = threadIdx.x;
    int wave = tid >> 6, lane = tid & 63;
    int grp = lane >> 4, rl = lane & 15;

    if (tid < 128) sbias[tid] = bias[tid];
    if (tid < 16) sda[tid] = fabsf(sdinv[blockIdx.x * 16 + tid]);

    // ---- spmm phase (verified math incl. da row-norm) ----
    int ch = rl * 8;
    int lg = wave * 4 + grp;
    int row = blockIdx.x * 16 + lg;
    bool ok = row < N;
    int p = 0, deg = 0, fd = 0;
    float sd = 0.f;
    h8v hs = {};
    if (ok) {
        p = rs[row];
        int dp = degpk[row];
        deg = dp & 0xffff; fd = dp >> 16;
        sd = sdinv[row];
        hs = *(const h8v*)&xs[(size_t)row * HID + ch];
    }
    int ud = deg - fd;
    int pd = (deg + 7) & ~7;
    int t1 = max(pd, __shfl_xor(pd, 16));
    int m  = max(t1, __shfl_xor(t1, 32));
    float U[8] = {}, F[8] = {};
    for (int i = 0; i < m; i += 16) {
        int id[16];
#pragma unroll
        for (int k = 0; k < 16; ++k) {
            int raw = (int)csr[p + i + k];
            id[k] = (i + k < pd) ? raw : N;
        }
        h8v h[16];
#pragma unroll
        for (int k = 0; k < 16; ++k) h[k] = *(const h8v*)&xs[(size_t)id[k] * HID + ch];
        h8v s0 = (h[0] + h[1]) + (h[2] + h[3]);
        h8v s1 = (h[4] + h[5]) + (h[6] + h[7]);
        h8v s2 = (h[8] + h[9]) + (h[10] + h[11]);
        h8v s3 = (h[12] + h[13]) + (h[14] + h[15]);
        h8v s  = (s0 + s1) + (s2 + s3);
#pragma unroll
        for (int j = 0; j < 8; ++j) U[j] += (float)s[j];
        if (i + 16 > ud) {
#pragma unroll
            for (int k = 0; k < 16; ++k) {
                if (i + k >= ud && i + k < deg) {
#pragma unroll
                    for (int j = 0; j < 8; ++j) F[j] += (float)h[k][j];
                }
            }
        }
    }
    {
        float da = fabsf(sd);
        float keep = (sd < 0.f) ? 0.f : 1.f;
        h8v lo = {}, hi = {};
        if (ok) {
#pragma unroll
            for (int j = 0; j < 8; ++j) {
                float f = (float)hs[j];
                lo[j] = (_Float16)(da * (U[j] + f));
                hi[j] = (_Float16)(da * (U[j] - F[j] + keep * f));
            }
        }
        *(h8v*)&sAgg[(2 * lg) * 136 + ch] = lo;
        *(h8v*)&sAgg[(2 * lg + 1) * 136 + ch] = hi;
    }
    __syncthreads();

    // ---- MFMA phase: A from sAgg (LDS), B from global W1T (L1/L2-resident, 32 KB) ----
    int g = lane >> 4;
    int rowtile = (wave & 1) * 16;
    int colbase = (wave >> 1) * 64;
    f4v acc[4];
#pragma unroll
    for (int cc = 0; cc < 4; ++cc) acc[cc] = (f4v){0.f, 0.f, 0.f, 0.f};
#pragma unroll
    for (int kb = 0; kb < 4; ++kb) {
        int k0 = kb * 32 + g * 8;
        h8v av = *(const h8v*)&sAgg[(rowtile + rl) * 136 + k0];
        h8v bv0 = *(const h8v*)&W1T[(colbase + 0 * 16 + rl) * 128 + k0];
        h8v bv1 = *(const h8v*)&W1T[(colbase + 1 * 16 + rl) * 128 + k0];
        h8v bv2 = *(const h8v*)&W1T[(colbase + 2 * 16 + rl) * 128 + k0];
        h8v bv3 = *(const h8v*)&W1T[(colbase + 3 * 16 + rl) * 128 + k0];
        acc[0] = __builtin_amdgcn_mfma_f32_16x16x32_f16(bv0, av, acc[0], 0, 0, 0);
        acc[1] = __builtin_amdgcn_mfma_f32_16x16x32_f16(bv1, av, acc[1], 0, 0, 0);
        acc[2] = __builtin_amdgcn_mfma_f32_16x16x32_f16(bv2, av, acc[2], 0, 0, 0);
        acc[3] = __builtin_amdgcn_mfma_f32_16x16x32_f16(bv3, av, acc[3], 0, 0, 0);
    }
    __syncthreads();   // all sAgg reads done; smem becomes sC

    // ---- epilogue: bias+relu+dinv -> sC ----
    int lrow = rowtile + rl;
    float dsc = sda[lrow >> 1];
#pragma unroll
    for (int cc = 0; cc < 4; ++cc) {
        f4v v = acc[cc];
        int col = colbase + cc * 16 + g * 4;
#pragma unroll
        for (int i2 = 0; i2 < 4; ++i2) v[i2] = fmaxf(v[i2] + sbias[col + i2], 0.f) * dsc;
        *(f4v*)&sC[lrow * 132 + col] = v;
    }
    __syncthreads();

    // ---- coalesced store ----
    int sr = tid >> 3, ck = tid & 7;
    int gRow = blockIdx.x * 32 + sr;
    if (gRow < 2 * N) {
        const float* src = &sC[sr * 132 + ck * 16];
        h8v o0, o1;
#pragma unroll
        for (int j = 0; j < 8; ++j) { o0[j] = (_Float16)src[j]; o1[j] = (_Float16)src[8 + j]; }
        _Float16* dst = &H[(size_t)gRow * HID + ck * 16];
        *(h8v*)&dst[0] = o0;
        *(h8v*)&dst[8] = o1;
    }
}

// ---------------- layer-2 SpMM at batch rows over prescaled H[2N+2][128]: branchless 16-deep ----------------

__global__ __launch_bounds__(256) void k_spmm2(const _Float16* __restrict__ H, const int* __restrict__ rs,
                                               const int* __restrict__ degpk, const unsigned int* __restrict__ csr,
                                               const float* __restrict__ sdinv, const int* __restrict__ batch,
                                               _Float16* __restrict__ aggH2, int B, int N) {
    int wave = threadIdx.x >> 6, lane = threadIdx.x & 63;
    int grp = lane >> 5, rl = lane & 31;
    int ch = rl * 8;
    int ri = blockIdx.x * 8 + wave * 2 + grp;
    bool ok = ri < B;
    int p = 0, deg = 0, row = 0;
    float da = 0.f;
    h8v hs = {};
    if (ok) {
        row = batch[ri];
        p = rs[row];
        deg = degpk[row] & 0xffff;
        da = fabsf(sdinv[row]);
        hs = *(const h8v*)&H[(size_t)row * 256 + ch];
    }
    int pd = (deg + 7) & ~7;
    int m = max(pd, __shfl_xor(pd, 32));
    float a[8] = {};
    for (int i = 0; i < m; i += 16) {
        int id[16];
#pragma unroll
        for (int k = 0; k < 16; ++k) {
            int raw = (int)csr[p + i + k];
            id[k] = (i + k < pd) ? raw : N;
        }
        h8v h[16];
#pragma unroll
        for (int k = 0; k < 16; ++k) h[k] = *(const h8v*)&H[(size_t)id[k] * 256 + ch];
        h8v s0 = (h[0] + h[1]) + (h[2] + h[3]);
        h8v s1 = (h[4] + h[5]) + (h[6] + h[7]);
        h8v s2 = (h[8] + h[9]) + (h[10] + h[11]);
        h8v s3 = (h[12] + h[13]) + (h[14] + h[15]);
        h8v s  = (s0 + s1) + (s2 + s3);
#pragma unroll
        for (int j = 0; j < 8; ++j) a[j] += (float)s[j];
    }
    if (!ok) return;
    h8v o;
#pragma unroll
    for (int j = 0; j < 8; ++j) o[j] = (_Float16)(da * ((float)hs[j] + a[j]));
    *(h8v*)&aggH2[(size_t)ri * 256 + ch] = o;
}

// ---------------- MFMA GEMM with LDS-bounce epilogue (modes 1,2) ----------------

template<int MODE>
__global__ __launch_bounds__(256) void k_gemm(const _Float16* __restrict__ A, const _Float16* __restrict__ WT,
                                              const float* __restrict__ bias,
                                              float* __restrict__ outF, _Float16* __restrict__ outH, int n2) {
    __shared__ __align__(16) char smem[128 * 136 * 2];
    __shared__ float sbias[128];
    _Float16* sWT = (_Float16*)smem;
    float* sC = (float*)smem;
    int tid = threadIdx.x;
#pragma unroll
    for (int it = 0; it < 8; ++it) {
        int lin = (it * 256 + tid) * 8;
        int c = lin >> 7, k = lin & 127;
        *(h8v*)&sWT[c * 136 + k] = *(const h8v*)&WT[lin];
    }
    if (MODE != 2) { if (tid < 128) sbias[tid] = bias[tid]; }
    __syncthreads();

    int wave = tid >> 6, lane = tid & 63;
    int rl = lane & 15, g = lane >> 4;
    int r = blockIdx.x * 64 + wave * 16 + rl;
    bool rok = r < n2;
    f4v acc[8];
#pragma unroll
    for (int cf = 0; cf < 8; ++cf) acc[cf] = (f4v){0.f, 0.f, 0.f, 0.f};
#pragma unroll
    for (int kb = 0; kb < 4; ++kb) {
        int k0 = kb * 32 + g * 8;
        h8v av = {};
        if (rok) av = *(const h8v*)&A[(size_t)r * HID + k0];
#pragma unroll
        for (int cf = 0; cf < 8; ++cf) {
            h8v bv = *(const h8v*)&sWT[(cf * 16 + rl) * 136 + k0];
            acc[cf] = __builtin_amdgcn_mfma_f32_16x16x32_f16(bv, av, acc[cf], 0, 0, 0);
        }
    }
    __syncthreads();
    int lrow = wave * 16 + rl;
#pragma unroll
    for (int cf = 0; cf < 8; ++cf) {
        f4v v = acc[cf];
        if (MODE != 2) {
            int chh = cf * 16 + g * 4;
#pragma unroll
            for (int i2 = 0; i2 < 4; ++i2) v[i2] = fmaxf(v[i2] + sbias[chh + i2], 0.f);
        }
        *(f4v*)&sC[lrow * 132 + cf * 16 + g * 4] = v;
    }
    __syncthreads();
    int lr = tid >> 2, seg = tid & 3;
    int R = blockIdx.x * 64 + lr;
    if (R < n2) {
        const float* src = &sC[lr * 132 + seg * 32];
        if (MODE == 1 && (R & 1) == 0) {
            float* dst = &outF[(size_t)(R >> 1) * HID + seg * 32];
#pragma unroll
            for (int qq = 0; qq < 8; ++qq) *(float4*)&dst[qq * 4] = *(const float4*)&src[qq * 4];
        } else {
            _Float16* dst;
            if (MODE == 1) dst = &outH[(size_t)(R >> 1) * HID + seg * 32];
            else dst = &outH[(size_t)R * HID + seg * 32];
#pragma unroll
            for (int qq = 0; qq < 4; ++qq) {
                h8v o;
#pragma unroll
                for (int j = 0; j < 8; ++j) o[j] = (_Float16)src[qq * 8 + j];
                *(h8v*)&dst[qq * 8] = o;
            }
        }
    }
}

// ---------------- heads ----------------

__global__ __launch_bounds__(256) void k_possum(const float* __restrict__ gf, const int* __restrict__ batch,
                                                const int* __restrict__ labels, float* __restrict__ yv,
                                                float* __restrict__ part, float* __restrict__ pos_part) {
    __shared__ float s[256];
    __shared__ float sy[256];
    int t = threadIdx.x;
    int r0 = blockIdx.x * 256;
    int b = r0 + t;
    float y = (labels[batch[b]] == 1) ? 1.f : 0.f;
    yv[b] = y;
    sy[t] = y;
    __syncthreads();
    int ch = t & 127, half = t >> 7;
    float acc = 0.f;
    for (int r = half; r < 256; r += 2) acc += sy[r] * gf[(size_t)(r0 + r) * HID + ch];
    s[t] = acc;
    __syncthreads();
    if (t < 128) part[blockIdx.x * 128 + t] = s[t] + s[t + 128];
    __syncthreads();
    s[t] = sy[t];
    __syncthreads();
    for (int st = 128; st > 0; st >>= 1) {
        if (t < st) s[t] += s[t + st];
        __syncthreads();
    }
    if (t == 0) pos_part[blockIdx.x] = s[0];
}

__global__ __launch_bounds__(128) void k_ctxvec(const float* __restrict__ Wctx, const float* __restrict__ part,
                                                const float* __restrict__ pos_part, float* v, float* pcnt) {
    __shared__ float sproto[128];
    __shared__ float spc;
    int t = threadIdx.x;
    if (t == 0) {
        float pc = 0.f;
        for (int i = 0; i < 16; ++i) pc += pos_part[i];
        spc = pc;
        pcnt[0] = pc;
    }
    float ssum = 0.f;
    for (int i = 0; i < 16; ++i) ssum += part[i * 128 + t];
    __syncthreads();
    sproto[t] = ssum / spc;
    __syncthreads();
    float acc = 0.f;
#pragma unroll 4
    for (int j = 0; j < 128; ++j) acc += Wctx[t * 128 + j] * sproto[j];
    v[t] = acc;
}

__global__ __launch_bounds__(256) void k_heads(const float* __restrict__ gf, const _Float16* __restrict__ T,
                                               const float* __restrict__ v, const float* __restrict__ yv,
                                               const float* __restrict__ bctx, const float* __restrict__ bloc,
                                               float* pA, float* pB, int B) {
    int wave = threadIdx.x >> 6, lane = threadIdx.x & 63;
    int b = blockIdx.x * 4 + wave;
    if (b >= B) return;
    float2 g = *(const float2*)&gf[(size_t)b * HID + lane * 2];
    h2v tt = *(const h2v*)&T[(size_t)b * HID + lane * 2];
    float2 vv = *(const float2*)&v[lane * 2];
    float s1 = g.x * vv.x + g.y * vv.y;
    float s2 = g.x * (float)tt[0] + g.y * (float)tt[1];
    for (int o = 32; o > 0; o >>= 1) {
        s1 += __shfl_xor(s1, o);
        s2 += __shfl_xor(s2, o);
    }
    if (lane == 0) {
        float y = yv[b];
        float z1 = s1 + bctx[0];
        float z2 = s2 + bloc[0];
        pA[b] = fmaxf(z1, 0.f) + log1pf(expf(-fabsf(z1))) - z1 * y;
        pB[b] = fmaxf(z2, 0.f) + log1pf(expf(-fabsf(z2))) - z2 * (1.f - y);
    }
}

__global__ __launch_bounds__(256) void k_final(const float* __restrict__ pA, const float* __restrict__ pB,
                                               const float* __restrict__ pcnt, float* out_loss, int B) {
    __shared__ float s1[256];
    __shared__ float s2[256];
    int t = threadIdx.x;
    float a = 0.f, b2 = 0.f;
    for (int i = t; i < B; i += 256) { a += pA[i]; b2 += pB[i]; }
    s1[t] = a;
    s2[t] = b2;
    __syncthreads();
    for (int st = 128; st > 0; st >>= 1) {
        if (t < st) { s1[t] += s1[t + st]; s2[t] += s2[t + st]; }
        __syncthreads();
    }
    if (t == 0) {
        float pc = pcnt[0];
        float nc = (float)B - pc;
        float total = 0.5f * (s1[0] / (float)B) + 0.5f * (s2[0] / (float)B);
        out_loss[0] = (pc > 0.f && nc > 0.f) ? total : 0.f;
    }
}

// ---------------- launcher ----------------

extern "C" void kernel_launch(void* const* d_in, const int* in_sizes, int n_in,
                              void* d_out, int out_size, void* d_ws, size_t ws_size,
                              hipStream_t stream) {
    const float* x      = (const float*)d_in[0];
    const int*   ei     = (const int*)d_in[1];
    const int*   batch  = (const int*)d_in[2];
    const int*   labels = (const int*)d_in[3];
    const float* W1     = (const float*)d_in[4];
    const float* b1     = (const float*)d_in[5];
    const float* W2     = (const float*)d_in[6];
    const float* b2     = (const float*)d_in[7];
    const float* Wctx   = (const float*)d_in[8];
    const float* bctx   = (const float*)d_in[9];
    const float* Wloc   = (const float*)d_in[10];
    const float* bloc   = (const float*)d_in[11];

    int N = in_sizes[0] / HID;
    int E = in_sizes[1] / 2;
    int B = in_sizes[2];
    float* out = (float*)d_out;

    char* wsb = (char*)d_ws;
    size_t off = 0;
    auto alloc = [&](size_t bytes) -> char* {
        char* p = wsb + off;
        off += (bytes + 255) & ~(size_t)255;
        return p;
    };
    int NB = ceil_div(N, 256);
    int mw = ceil_div(N, 32);

    _Float16* xs   = (_Float16*)alloc((size_t)(N + 1) * HID * 2);
    _Float16* H    = (_Float16*)alloc((size_t)(2 * N + 2) * HID * 2);
    unsigned int* ebuf = (unsigned int*)alloc((size_t)NB * CAP * 4);
    unsigned int* csr  = (unsigned int*)alloc((size_t)NB * CAP * 4);
    float* sdinv = (float*)alloc((size_t)N * 4);
    int*   rs    = (int*)alloc((size_t)N * 4);
    int*   degpk = (int*)alloc((size_t)N * 4);
    int*   bcur  = (int*)alloc((size_t)NB * 4);
    unsigned int* mask = (unsigned int*)alloc((size_t)mw * 4);
    _Float16* W1T = (_Float16*)alloc(128 * 128 * 2);
    _Float16* W2T = (_Float16*)alloc(128 * 128 * 2);
    _Float16* WlT = (_Float16*)alloc(128 * 128 * 2);
    _Float16* aggH2 = (_Float16*)alloc((size_t)B * 256 * 2);
    _Float16* envh  = (_Float16*)alloc((size_t)B * HID * 2);
    _Float16* Tt    = (_Float16*)alloc((size_t)B * HID * 2);
    float* yv   = (float*)alloc((size_t)B * 4);
    float* pos_part = (float*)alloc(64 * 4);
    float* part     = (float*)alloc(16 * 128 * 4);
    float* vvec     = (float*)alloc(128 * 4);
    float* pcnt     = (float*)alloc(256);
    float* pA       = (float*)alloc((size_t)B * 4);
    float* pB       = (float*)alloc((size_t)B * 4);
    (void)ws_size; (void)n_in; (void)out_size;

    int NBLKE = ceil_div(E, EPB);
    int NBLKB = ceil_div(B, 1024);

    k_setup<<<192 + ceil_div(mw, 256), 256, 0, stream>>>(W1, W2, Wloc, W1T, W2T, WlT, mask, bcur, mw, NB);
    k_partA<<<NBLKE + NBLKB, 1024, 0, stream>>>(ei, bcur, ebuf, batch, mask, E, B, NB, NBLKE);
    k_csr<<<NB, 256, 0, stream>>>(ebuf, bcur, mask, x, sdinv, rs, degpk, csr, xs, H, N);

    // fused layer 1 (low-LDS variant)
    k_layer1<<<ceil_div(N, 16), 256, 0, stream>>>(xs, rs, degpk, csr, sdinv, W1T, b1, H, N);

    k_spmm2<<<ceil_div(B, 8), 256, 0, stream>>>(H, rs, degpk, csr, sdinv, batch, aggH2, B, N);
    k_gemm<1><<<ceil_div(2 * B, 64), 256, 0, stream>>>(aggH2, W2T, b2, out, envh, 2 * B);
    k_gemm<2><<<ceil_div(B, 64), 256, 0, stream>>>(envh, WlT, nullptr, nullptr, Tt, B);

    k_possum<<<16, 256, 0, stream>>>(out, batch, labels, yv, part, pos_part);
    k_ctxvec<<<1, 128, 0, stream>>>(Wctx, part, pos_part, vvec, pcnt);
    k_heads<<<ceil_div(B, 4), 256, 0, stream>>>(out, Tt, vvec, yv, bctx, bloc, pA, pB, B);
    k_final<<<1, 256, 0, stream>>>(pA, pB, pcnt, out + (size_t)B * HID, B);
}

// Round 11
// 176.543 us; speedup vs baseline: 1.0949x; 1.0949x over previous
//
#include <hip/hip_runtime.h>
#include <math.h>

#define HID 128
#define CAP 12288                // padded edges per 256-node bucket
#define NBUCK_MAX 256
#define EPB 8192                 // edges per partA block

typedef _Float16 h2v __attribute__((ext_vector_type(2)));
typedef _Float16 h8v __attribute__((ext_vector_type(8)));
typedef float f4v __attribute__((ext_vector_type(4)));

static inline int ceil_div(int a, int b) { return (a + b - 1) / b; }

// ---------------- setup: transpose weights to fp16, init mask/bcur ----------------

__global__ __launch_bounds__(256) void k_setup(const float* __restrict__ W1, const float* __restrict__ W2,
                                               const float* __restrict__ Wl, _Float16* T1, _Float16* T2,
                                               _Float16* Tl, unsigned int* mask, int* bcur, int mw, int NB) {
    int b = blockIdx.x;
    if (b < 192) {
        int which = b >> 6;
        int idx = (b & 63) * 256 + threadIdx.x;
        int k = idx >> 7, c = idx & 127;
        const float* S = (which == 0) ? W1 : ((which == 1) ? W2 : Wl);
        _Float16* D = (which == 0) ? T1 : ((which == 1) ? T2 : Tl);
        D[c * 128 + k] = (_Float16)S[idx];
    } else {
        int i = (b - 192) * 256 + threadIdx.x;
        if (i < mw) mask[i] = 0u;
        if (i < NB) bcur[i] = i * CAP;
    }
}

// ---------------- bucket partition with block-local counting sort + burst copy-out ----------------

__global__ __launch_bounds__(1024) void k_partA(const int* __restrict__ ei, int* __restrict__ bcur,
                                                unsigned int* __restrict__ ebuf,
                                                const int* __restrict__ batch, unsigned int* mask,
                                                int E, int B, int NB, int NBLKE) {
    if ((int)blockIdx.x >= NBLKE) {
        int i = ((int)blockIdx.x - NBLKE) * 1024 + threadIdx.x;
        if (i < B) { int nd = batch[i]; atomicOr(&mask[nd >> 5], 1u << (nd & 31)); }
        return;
    }
    __shared__ int lcnt[NBUCK_MAX];
    __shared__ int sc[NBUCK_MAX];
    __shared__ int lcur[NBUCK_MAX];
    __shared__ int gbase[NBUCK_MAX];
    __shared__ unsigned int se[EPB];
    int tid = threadIdx.x;
    if (tid < NBUCK_MAX) lcnt[tid] = 0;
    __syncthreads();
    int base = blockIdx.x * EPB;
    unsigned int pk[8];
    int bk[8];
#pragma unroll
    for (int j = 0; j < 8; ++j) {
        int e = base + tid + j * 1024;
        if (e < E) {
            int s = ei[e], d = ei[E + e];
            pk[j] = ((unsigned int)s << 8) | (unsigned int)(d & 255);
            bk[j] = d >> 8;
            atomicAdd(&lcnt[bk[j]], 1);
        } else bk[j] = -1;
    }
    __syncthreads();
    if (tid < NBUCK_MAX) sc[tid] = lcnt[tid];
    __syncthreads();
    for (int off = 1; off < NBUCK_MAX; off <<= 1) {
        int v = 0;
        if (tid < NBUCK_MAX && tid >= off) v = sc[tid - off];
        __syncthreads();
        if (tid < NBUCK_MAX) sc[tid] += v;
        __syncthreads();
    }
    if (tid < NBUCK_MAX) {
        int cc = lcnt[tid];
        int lo = sc[tid] - cc;
        lcur[tid] = lo;
        gbase[tid] = cc ? atomicAdd(&bcur[tid], cc) : 0;
    }
    __syncthreads();
#pragma unroll
    for (int j = 0; j < 8; ++j) {
        if (bk[j] >= 0) {
            int r = atomicAdd(&lcur[bk[j]], 1);
            se[r] = pk[j];
        }
    }
    __syncthreads();
    int wid = tid >> 6, lane = tid & 63;
    for (int b = wid; b < NB; b += 16) {
        int cc = lcnt[b];
        int lo = sc[b] - cc;
        int go = gbase[b];
        for (int i = lane; i < cc; i += 64) ebuf[go + i] = se[lo + i];
    }
}

// ---------------- one-pass CSR (pad to x8) + fused xs cast + zero pad rows ----------------

__global__ __launch_bounds__(256) void k_csr(const unsigned int* __restrict__ ebuf, const int* __restrict__ bcur,
                                             const unsigned int* __restrict__ mask, const float* __restrict__ x,
                                             float* __restrict__ sdinv, int* __restrict__ rs,
                                             int* __restrict__ degpk, unsigned int* __restrict__ csr,
                                             _Float16* __restrict__ xs, _Float16* __restrict__ H, int N) {
    __shared__ unsigned int se[CAP];
    __shared__ int deg[256];
    __shared__ int fde[256];
    __shared__ int sc[256];
    __shared__ int cu[256];
    __shared__ int cf[256];
    __shared__ float sda[256];
    int b = blockIdx.x, t = threadIdx.x;
    deg[t] = 0; fde[t] = 0;
    __syncthreads();
    int base = b * CAP;
    int ecnt = bcur[b] - base;
    for (int i = t; i < ecnt; i += 256) {
        unsigned int v = ebuf[base + i];
        int s = v >> 8;
        int fl = (mask[s >> 5] >> (s & 31)) & 1;
        se[i] = ((unsigned int)s << 9) | ((unsigned int)fl << 8) | (v & 255);
        atomicAdd(&deg[v & 255], 1);
        if (fl) atomicAdd(&fde[v & 255], 1);
    }
    __syncthreads();
    int dv = deg[t], fv = fde[t];
    int pv = (dv + 7) & ~7;
    sc[t] = pv;
    __syncthreads();
    for (int off = 1; off < 256; off <<= 1) {
        int v2 = (t >= off) ? sc[t - off] : 0;
        __syncthreads();
        sc[t] += v2;
        __syncthreads();
    }
    int r0 = base + sc[t] - pv;
    cu[t] = r0;
    cf[t] = r0 + (dv - fv);
    int node = b * 256 + t;
    float da = 0.f;
    if (node < N) {
        rs[node] = r0;
        degpk[node] = dv | (fv << 16);
        float di = rsqrtf((float)(dv + 1));
        da = di;
        if ((mask[node >> 5] >> (node & 31)) & 1) di = -di;
        sdinv[node] = di;
    }
    sda[t] = da;
    __syncthreads();
    for (int i = t; i < ecnt; i += 256) {
        unsigned int v = se[i];
        int d8 = v & 255;
        int p = ((v >> 8) & 1) ? atomicAdd(&cf[d8], 1) : atomicAdd(&cu[d8], 1);
        csr[p] = v >> 9;
    }
    if (node < N) {
        for (int j = dv; j < pv; ++j) csr[r0 + j] = (unsigned int)N;
    }
    int nl0 = b * 256;
    int nmax = min(256, N - nl0);
    for (int idx = t; idx < nmax * 16; idx += 256) {
        int nl = idx >> 4, chunk = idx & 15;
        float dda = sda[nl];
        size_t o = (size_t)(nl0 + nl) * HID + chunk * 8;
        float4 a = *(const float4*)&x[o];
        float4 bb = *(const float4*)&x[o + 4];
        h8v v;
        v[0] = (_Float16)(a.x * dda); v[1] = (_Float16)(a.y * dda);
        v[2] = (_Float16)(a.z * dda); v[3] = (_Float16)(a.w * dda);
        v[4] = (_Float16)(bb.x * dda); v[5] = (_Float16)(bb.y * dda);
        v[6] = (_Float16)(bb.z * dda); v[7] = (_Float16)(bb.w * dda);
        *(h8v*)&xs[o] = v;
    }
    if (b == 0) {
        if (t < 16) *(h8v*)&xs[(size_t)N * HID + t * 8] = (h8v){};
        else if (t < 48) *(h8v*)&H[(size_t)2 * N * HID + (t - 16) * 8] = (h8v){};
    }
}

// ---------------- fused layer 1 (round-9 proven variant): SpMM + MFMA (W1T in LDS) -> H ----------------

__global__ __launch_bounds__(256) void k_layer1(const _Float16* __restrict__ xs, const int* __restrict__ rs,
                                                const int* __restrict__ degpk, const unsigned int* __restrict__ csr,
                                                const float* __restrict__ sdinv, const _Float16* __restrict__ W1T,
                                                const float* __restrict__ bias, _Float16* __restrict__ H, int N) {
    __shared__ __align__(16) _Float16 sWT[128 * 136];   // 34.8 KB, overlaid by sC in epilogue
    __shared__ __align__(16) _Float16 sAgg[32 * 136];   // 8.7 KB
    __shared__ float sbias[128];
    __shared__ float sda[16];
    float* sC = (float*)sWT;

    int tid = threadIdx.x;
    int wave = tid >> 6, lane = tid & 63;
    int grp = lane >> 4, rl = lane & 15;

#pragma unroll
    for (int it = 0; it < 8; ++it) {
        int lin = (it * 256 + tid) * 8;
        int c = lin >> 7, k = lin & 127;
        *(h8v*)&sWT[c * 136 + k] = *(const h8v*)&W1T[lin];
    }
    if (tid < 128) sbias[tid] = bias[tid];
    if (tid < 16) sda[tid] = fabsf(sdinv[blockIdx.x * 16 + tid]);

    int ch = rl * 8;
    int lg = wave * 4 + grp;
    int row = blockIdx.x * 16 + lg;
    bool ok = row < N;
    int p = 0, deg = 0, fd = 0;
    float sd = 0.f;
    h8v hs = {};
    if (ok) {
        p = rs[row];
        int dp = degpk[row];
        deg = dp & 0xffff; fd = dp >> 16;
        sd = sdinv[row];
        hs = *(const h8v*)&xs[(size_t)row * HID + ch];
    }
    int ud = deg - fd;
    int pd = (deg + 7) & ~7;
    int t1 = max(pd, __shfl_xor(pd, 16));
    int m  = max(t1, __shfl_xor(t1, 32));
    float U[8] = {}, F[8] = {};
    for (int i = 0; i < m; i += 16) {
        int id[16];
#pragma unroll
        for (int k = 0; k < 16; ++k) {
            int raw = (int)csr[p + i + k];
            id[k] = (i + k < pd) ? raw : N;
        }
        h8v h[16];
#pragma unroll
        for (int k = 0; k < 16; ++k) h[k] = *(const h8v*)&xs[(size_t)id[k] * HID + ch];
        h8v s0 = (h[0] + h[1]) + (h[2] + h[3]);
        h8v s1 = (h[4] + h[5]) + (h[6] + h[7]);
        h8v s2 = (h[8] + h[9]) + (h[10] + h[11]);
        h8v s3 = (h[12] + h[13]) + (h[14] + h[15]);
        h8v s  = (s0 + s1) + (s2 + s3);
#pragma unroll
        for (int j = 0; j < 8; ++j) U[j] += (float)s[j];
        if (i + 16 > ud) {
#pragma unroll
            for (int k = 0; k < 16; ++k) {
                if (i + k >= ud && i + k < deg) {
#pragma unroll
                    for (int j = 0; j < 8; ++j) F[j] += (float)h[k][j];
                }
            }
        }
    }
    {
        float da = fabsf(sd);                     // row-norm factor (round-9 verified)
        float keep = (sd < 0.f) ? 0.f : 1.f;
        h8v lo = {}, hi = {};
        if (ok) {
#pragma unroll
            for (int j = 0; j < 8; ++j) {
                float f = (float)hs[j];
                lo[j] = (_Float16)(da * (U[j] + f));
                hi[j] = (_Float16)(da * (U[j] - F[j] + keep * f));
            }
        }
        *(h8v*)&sAgg[(2 * lg) * 136 + ch] = lo;
        *(h8v*)&sAgg[(2 * lg + 1) * 136 + ch] = hi;
    }
    __syncthreads();

    int g = lane >> 4;
    int rowtile = (wave & 1) * 16;
    int colbase = (wave >> 1) * 64;
    f4v acc[4];
#pragma unroll
    for (int cc = 0; cc < 4; ++cc) acc[cc] = (f4v){0.f, 0.f, 0.f, 0.f};
#pragma unroll
    for (int kb = 0; kb < 4; ++kb) {
        int k0 = kb * 32 + g * 8;
        h8v av = *(const h8v*)&sAgg[(rowtile + rl) * 136 + k0];
#pragma unroll
        for (int cc = 0; cc < 4; ++cc) {
            h8v bv = *(const h8v*)&sWT[(colbase + cc * 16 + rl) * 136 + k0];
            acc[cc] = __builtin_amdgcn_mfma_f32_16x16x32_f16(bv, av, acc[cc], 0, 0, 0);
        }
    }
    __syncthreads();   // all sWT reads done; overlay as sC

    int lrow = rowtile + rl;
    float dsc = sda[lrow >> 1];
#pragma unroll
    for (int cc = 0; cc < 4; ++cc) {
        f4v v = acc[cc];
        int col = colbase + cc * 16 + g * 4;
#pragma unroll
        for (int i2 = 0; i2 < 4; ++i2) v[i2] = fmaxf(v[i2] + sbias[col + i2], 0.f) * dsc;
        *(f4v*)&sC[lrow * 132 + col] = v;
    }
    __syncthreads();

    int sr = tid >> 3, ck = tid & 7;
    int gRow = blockIdx.x * 32 + sr;
    if (gRow < 2 * N) {
        const float* src = &sC[sr * 132 + ck * 16];
        h8v o0, o1;
#pragma unroll
        for (int j = 0; j < 8; ++j) { o0[j] = (_Float16)src[j]; o1[j] = (_Float16)src[8 + j]; }
        _Float16* dst = &H[(size_t)gRow * HID + ck * 16];
        *(h8v*)&dst[0] = o0;
        *(h8v*)&dst[8] = o1;
    }
}

// ---------------- fused layer 2: batch SpMM (8-deep, both views) + MFMA (W2T in LDS) -> gf/env ----------------
// block = 16 batch rows (4 waves), 32 A-rows: local 2*lg = normal agg, 2*lg+1 = env agg

__global__ __launch_bounds__(256) void k_layer2(const _Float16* __restrict__ H, const int* __restrict__ rs,
                                                const int* __restrict__ degpk, const unsigned int* __restrict__ csr,
                                                const float* __restrict__ sdinv, const int* __restrict__ batch,
                                                const _Float16* __restrict__ W2T, const float* __restrict__ bias,
                                                float* __restrict__ gf, _Float16* __restrict__ envh, int B, int N) {
    __shared__ __align__(16) _Float16 sWT[128 * 136];
    __shared__ __align__(16) _Float16 sAgg[32 * 136];
    __shared__ float sbias[128];
    float* sC = (float*)sWT;

    int tid = threadIdx.x;
    int wave = tid >> 6, lane = tid & 63;
    int grp = lane >> 4, rl = lane & 15;

#pragma unroll
    for (int it = 0; it < 8; ++it) {
        int lin = (it * 256 + tid) * 8;
        int c = lin >> 7, k = lin & 127;
        *(h8v*)&sWT[c * 136 + k] = *(const h8v*)&W2T[lin];
    }
    if (tid < 128) sbias[tid] = bias[tid];

    // ---- spmm phase: each 16-lane group = one batch row, both views per edge ----
    int ch = rl * 8;
    int lg = wave * 4 + grp;
    int ri = blockIdx.x * 16 + lg;
    bool ok = ri < B;
    int p = 0, deg = 0, row = 0;
    float da = 0.f;
    h8v hn = {}, he = {};
    if (ok) {
        row = batch[ri];
        p = rs[row];
        deg = degpk[row] & 0xffff;
        da = fabsf(sdinv[row]);
        hn = *(const h8v*)&H[(size_t)row * 256 + ch];
        he = *(const h8v*)&H[(size_t)row * 256 + 128 + ch];
    }
    int pd = (deg + 7) & ~7;
    int t1 = max(pd, __shfl_xor(pd, 16));
    int m  = max(t1, __shfl_xor(t1, 32));
    float a[8] = {}, e[8] = {};
    for (int i = 0; i < m; i += 8) {
        int id[8];
#pragma unroll
        for (int k = 0; k < 8; ++k) {
            int raw = (int)csr[p + i + k];
            id[k] = (i + k < pd) ? raw : N;
        }
        h8v xn[8], xe[8];
#pragma unroll
        for (int k = 0; k < 8; ++k) {
            xn[k] = *(const h8v*)&H[(size_t)id[k] * 256 + ch];
            xe[k] = *(const h8v*)&H[(size_t)id[k] * 256 + 128 + ch];
        }
        h8v sn = ((xn[0] + xn[1]) + (xn[2] + xn[3])) + ((xn[4] + xn[5]) + (xn[6] + xn[7]));
        h8v sv = ((xe[0] + xe[1]) + (xe[2] + xe[3])) + ((xe[4] + xe[5]) + (xe[6] + xe[7]));
#pragma unroll
        for (int j = 0; j < 8; ++j) { a[j] += (float)sn[j]; e[j] += (float)sv[j]; }
    }
    {
        h8v lo = {}, hi = {};
        if (ok) {
#pragma unroll
            for (int j = 0; j < 8; ++j) {
                lo[j] = (_Float16)(da * (a[j] + (float)hn[j]));
                hi[j] = (_Float16)(da * (e[j] + (float)he[j]));
            }
        }
        *(h8v*)&sAgg[(2 * lg) * 136 + ch] = lo;
        *(h8v*)&sAgg[(2 * lg + 1) * 136 + ch] = hi;
    }
    __syncthreads();

    // ---- MFMA phase (layer1 geometry) ----
    int g = lane >> 4;
    int rowtile = (wave & 1) * 16;
    int colbase = (wave >> 1) * 64;
    f4v acc[4];
#pragma unroll
    for (int cc = 0; cc < 4; ++cc) acc[cc] = (f4v){0.f, 0.f, 0.f, 0.f};
#pragma unroll
    for (int kb = 0; kb < 4; ++kb) {
        int k0 = kb * 32 + g * 8;
        h8v av = *(const h8v*)&sAgg[(rowtile + rl) * 136 + k0];
#pragma unroll
        for (int cc = 0; cc < 4; ++cc) {
            h8v bv = *(const h8v*)&sWT[(colbase + cc * 16 + rl) * 136 + k0];
            acc[cc] = __builtin_amdgcn_mfma_f32_16x16x32_f16(bv, av, acc[cc], 0, 0, 0);
        }
    }
    __syncthreads();

    // ---- epilogue: bias+relu (no post-scale) -> sC ----
    int lrow = rowtile + rl;
#pragma unroll
    for (int cc = 0; cc < 4; ++cc) {
        f4v v = acc[cc];
        int col = colbase + cc * 16 + g * 4;
#pragma unroll
        for (int i2 = 0; i2 < 4; ++i2) v[i2] = fmaxf(v[i2] + sbias[col + i2], 0.f);
        *(f4v*)&sC[lrow * 132 + col] = v;
    }
    __syncthreads();

    // ---- split store: even local row -> gf fp32, odd -> envh fp16 ----
    int sr = tid >> 3, ck = tid & 7;
    int ri2 = blockIdx.x * 16 + (sr >> 1);
    if (ri2 < B) {
        const float* src = &sC[sr * 132 + ck * 16];
        if ((sr & 1) == 0) {
            float* dst = &gf[(size_t)ri2 * HID + ck * 16];
#pragma unroll
            for (int q = 0; q < 4; ++q) *(float4*)&dst[q * 4] = *(const float4*)&src[q * 4];
        } else {
            h8v o0, o1;
#pragma unroll
            for (int j = 0; j < 8; ++j) { o0[j] = (_Float16)src[j]; o1[j] = (_Float16)src[8 + j]; }
            _Float16* dst = &envh[(size_t)ri2 * HID + ck * 16];
            *(h8v*)&dst[0] = o0;
            *(h8v*)&dst[8] = o1;
        }
    }
}

// ---------------- plain MFMA GEMM (T = env @ Wloc) ----------------

__global__ __launch_bounds__(256) void k_gemmT(const _Float16* __restrict__ A, const _Float16* __restrict__ WT,
                                               _Float16* __restrict__ outH, int n2) {
    __shared__ __align__(16) char smem[128 * 136 * 2];
    _Float16* sWT = (_Float16*)smem;
    float* sC = (float*)smem;
    int tid = threadIdx.x;
#pragma unroll
    for (int it = 0; it < 8; ++it) {
        int lin = (it * 256 + tid) * 8;
        int c = lin >> 7, k = lin & 127;
        *(h8v*)&sWT[c * 136 + k] = *(const h8v*)&WT[lin];
    }
    __syncthreads();

    int wave = tid >> 6, lane = tid & 63;
    int rl = lane & 15, g = lane >> 4;
    int r = blockIdx.x * 64 + wave * 16 + rl;
    bool rok = r < n2;
    f4v acc[8];
#pragma unroll
    for (int cf = 0; cf < 8; ++cf) acc[cf] = (f4v){0.f, 0.f, 0.f, 0.f};
#pragma unroll
    for (int kb = 0; kb < 4; ++kb) {
        int k0 = kb * 32 + g * 8;
        h8v av = {};
        if (rok) av = *(const h8v*)&A[(size_t)r * HID + k0];
#pragma unroll
        for (int cf = 0; cf < 8; ++cf) {
            h8v bv = *(const h8v*)&sWT[(cf * 16 + rl) * 136 + k0];
            acc[cf] = __builtin_amdgcn_mfma_f32_16x16x32_f16(bv, av, acc[cf], 0, 0, 0);
        }
    }
    __syncthreads();
    int lrow = wave * 16 + rl;
#pragma unroll
    for (int cf = 0; cf < 8; ++cf) {
        *(f4v*)&sC[lrow * 132 + cf * 16 + g * 4] = acc[cf];
    }
    __syncthreads();
    int lr = tid >> 2, seg = tid & 3;
    int R = blockIdx.x * 64 + lr;
    if (R < n2) {
        const float* src = &sC[lr * 132 + seg * 32];
        _Float16* dst = &outH[(size_t)R * HID + seg * 32];
#pragma unroll
        for (int qq = 0; qq < 4; ++qq) {
            h8v o;
#pragma unroll
            for (int j = 0; j < 8; ++j) o[j] = (_Float16)src[qq * 8 + j];
            *(h8v*)&dst[qq * 8] = o;
        }
    }
}

// ---------------- heads ----------------

__global__ __launch_bounds__(256) void k_possum(const float* __restrict__ gf, const int* __restrict__ batch,
                                                const int* __restrict__ labels, float* __restrict__ yv,
                                                float* __restrict__ part, float* __restrict__ pos_part) {
    __shared__ float s[256];
    __shared__ float sy[256];
    int t = threadIdx.x;
    int r0 = blockIdx.x * 256;
    int b = r0 + t;
    float y = (labels[batch[b]] == 1) ? 1.f : 0.f;
    yv[b] = y;
    sy[t] = y;
    __syncthreads();
    int ch = t & 127, half = t >> 7;
    float acc = 0.f;
    for (int r = half; r < 256; r += 2) acc += sy[r] * gf[(size_t)(r0 + r) * HID + ch];
    s[t] = acc;
    __syncthreads();
    if (t < 128) part[blockIdx.x * 128 + t] = s[t] + s[t + 128];
    __syncthreads();
    s[t] = sy[t];
    __syncthreads();
    for (int st = 128; st > 0; st >>= 1) {
        if (t < st) s[t] += s[t + st];
        __syncthreads();
    }
    if (t == 0) pos_part[blockIdx.x] = s[0];
}

__global__ __launch_bounds__(128) void k_ctxvec(const float* __restrict__ Wctx, const float* __restrict__ part,
                                                const float* __restrict__ pos_part, float* v, float* pcnt) {
    __shared__ float sproto[128];
    __shared__ float spc;
    int t = threadIdx.x;
    if (t == 0) {
        float pc = 0.f;
        for (int i = 0; i < 16; ++i) pc += pos_part[i];
        spc = pc;
        pcnt[0] = pc;
    }
    float ssum = 0.f;
    for (int i = 0; i < 16; ++i) ssum += part[i * 128 + t];
    __syncthreads();
    sproto[t] = ssum / spc;
    __syncthreads();
    float acc = 0.f;
#pragma unroll 4
    for (int j = 0; j < 128; ++j) acc += Wctx[t * 128 + j] * sproto[j];
    v[t] = acc;
}

__global__ __launch_bounds__(256) void k_heads(const float* __restrict__ gf, const _Float16* __restrict__ T,
                                               const float* __restrict__ v, const float* __restrict__ yv,
                                               const float* __restrict__ bctx, const float* __restrict__ bloc,
                                               float* pA, float* pB, int B) {
    int wave = threadIdx.x >> 6, lane = threadIdx.x & 63;
    int b = blockIdx.x * 4 + wave;
    if (b >= B) return;
    float2 g = *(const float2*)&gf[(size_t)b * HID + lane * 2];
    h2v tt = *(const h2v*)&T[(size_t)b * HID + lane * 2];
    float2 vv = *(const float2*)&v[lane * 2];
    float s1 = g.x * vv.x + g.y * vv.y;
    float s2 = g.x * (float)tt[0] + g.y * (float)tt[1];
    for (int o = 32; o > 0; o >>= 1) {
        s1 += __shfl_xor(s1, o);
        s2 += __shfl_xor(s2, o);
    }
    if (lane == 0) {
        float y = yv[b];
        float z1 = s1 + bctx[0];
        float z2 = s2 + bloc[0];
        pA[b] = fmaxf(z1, 0.f) + log1pf(expf(-fabsf(z1))) - z1 * y;
        pB[b] = fmaxf(z2, 0.f) + log1pf(expf(-fabsf(z2))) - z2 * (1.f - y);
    }
}

__global__ __launch_bounds__(256) void k_final(const float* __restrict__ pA, const float* __restrict__ pB,
                                               const float* __restrict__ pcnt, float* out_loss, int B) {
    __shared__ float s1[256];
    __shared__ float s2[256];
    int t = threadIdx.x;
    float a = 0.f, b2 = 0.f;
    for (int i = t; i < B; i += 256) { a += pA[i]; b2 += pB[i]; }
    s1[t] = a;
    s2[t] = b2;
    __syncthreads();
    for (int st = 128; st > 0; st >>= 1) {
        if (t < st) { s1[t] += s1[t + st]; s2[t] += s2[t + st]; }
        __syncthreads();
    }
    if (t == 0) {
        float pc = pcnt[0];
        float nc = (float)B - pc;
        float total = 0.5f * (s1[0] / (float)B) + 0.5f * (s2[0] / (float)B);
        out_loss[0] = (pc > 0.f && nc > 0.f) ? total : 0.f;
    }
}

// ---------------- launcher ----------------

extern "C" void kernel_launch(void* const* d_in, const int* in_sizes, int n_in,
                              void* d_out, int out_size, void* d_ws, size_t ws_size,
                              hipStream_t stream) {
    const float* x      = (const float*)d_in[0];
    const int*   ei     = (const int*)d_in[1];
    const int*   batch  = (const int*)d_in[2];
    const int*   labels = (const int*)d_in[3];
    const float* W1     = (const float*)d_in[4];
    const float* b1     = (const float*)d_in[5];
    const float* W2     = (const float*)d_in[6];
    const float* b2     = (const float*)d_in[7];
    const float* Wctx   = (const float*)d_in[8];
    const float* bctx   = (const float*)d_in[9];
    const float* Wloc   = (const float*)d_in[10];
    const float* bloc   = (const float*)d_in[11];

    int N = in_sizes[0] / HID;
    int E = in_sizes[1] / 2;
    int B = in_sizes[2];
    float* out = (float*)d_out;

    char* wsb = (char*)d_ws;
    size_t off = 0;
    auto alloc = [&](size_t bytes) -> char* {
        char* p = wsb + off;
        off += (bytes + 255) & ~(size_t)255;
        return p;
    };
    int NB = ceil_div(N, 256);
    int mw = ceil_div(N, 32);

    _Float16* xs   = (_Float16*)alloc((size_t)(N + 1) * HID * 2);
    _Float16* H    = (_Float16*)alloc((size_t)(2 * N + 2) * HID * 2);
    unsigned int* ebuf = (unsigned int*)alloc((size_t)NB * CAP * 4);
    unsigned int* csr  = (unsigned int*)alloc((size_t)NB * CAP * 4);
    float* sdinv = (float*)alloc((size_t)N * 4);
    int*   rs    = (int*)alloc((size_t)N * 4);
    int*   degpk = (int*)alloc((size_t)N * 4);
    int*   bcur  = (int*)alloc((size_t)NB * 4);
    unsigned int* mask = (unsigned int*)alloc((size_t)mw * 4);
    _Float16* W1T = (_Float16*)alloc(128 * 128 * 2);
    _Float16* W2T = (_Float16*)alloc(128 * 128 * 2);
    _Float16* WlT = (_Float16*)alloc(128 * 128 * 2);
    _Float16* envh  = (_Float16*)alloc((size_t)B * HID * 2);
    _Float16* Tt    = (_Float16*)alloc((size_t)B * HID * 2);
    float* yv   = (float*)alloc((size_t)B * 4);
    float* pos_part = (float*)alloc(64 * 4);
    float* part     = (float*)alloc(16 * 128 * 4);
    float* vvec     = (float*)alloc(128 * 4);
    float* pcnt     = (float*)alloc(256);
    float* pA       = (float*)alloc((size_t)B * 4);
    float* pB       = (float*)alloc((size_t)B * 4);
    (void)ws_size; (void)n_in; (void)out_size;

    int NBLKE = ceil_div(E, EPB);
    int NBLKB = ceil_div(B, 1024);

    k_setup<<<192 + ceil_div(mw, 256), 256, 0, stream>>>(W1, W2, Wloc, W1T, W2T, WlT, mask, bcur, mw, NB);
    k_partA<<<NBLKE + NBLKB, 1024, 0, stream>>>(ei, bcur, ebuf, batch, mask, E, B, NB, NBLKE);
    k_csr<<<NB, 256, 0, stream>>>(ebuf, bcur, mask, x, sdinv, rs, degpk, csr, xs, H, N);

    // fused layer 1 (round-9 proven variant)
    k_layer1<<<ceil_div(N, 16), 256, 0, stream>>>(xs, rs, degpk, csr, sdinv, W1T, b1, H, N);

    // fused layer 2: batch SpMM + W2 GEMM -> gf (fp32) + env (fp16)
    k_layer2<<<ceil_div(B, 16), 256, 0, stream>>>(H, rs, degpk, csr, sdinv, batch, W2T, b2, out, envh, B, N);

    // T = env @ Wloc
    k_gemmT<<<ceil_div(B, 64), 256, 0, stream>>>(envh, WlT, Tt, B);

    k_possum<<<16, 256, 0, stream>>>(out, batch, labels, yv, part, pos_part);
    k_ctxvec<<<1, 128, 0, stream>>>(Wctx, part, pos_part, vvec, pcnt);
    k_heads<<<ceil_div(B, 4), 256, 0, stream>>>(out, Tt, vvec, yv, bctx, bloc, pA, pB, B);
    k_final<<<1, 256, 0, stream>>>(pA, pB, pcnt, out + (size_t)B * HID, B);
}

// Round 12
// 145.787 us; speedup vs baseline: 1.3258x; 1.2110x over previous
//
#include <hip/hip_runtime.h>
#include <math.h>

#define HID 128
#define CAP 12288                // padded edges per 256-node bucket
#define NBUCK_MAX 256
#define EPB 8192                 // edges per partA block

typedef _Float16 h2v __attribute__((ext_vector_type(2)));
typedef _Float16 h8v __attribute__((ext_vector_type(8)));
typedef float f4v __attribute__((ext_vector_type(4)));

static inline int ceil_div(int a, int b) { return (a + b - 1) / b; }

// ---------------- setup: transpose weights to fp16, init mask/bcur, zero accumulators ----------------

__global__ __launch_bounds__(256) void k_setup(const float* __restrict__ W1, const float* __restrict__ W2,
                                               const float* __restrict__ Wl, _Float16* T1, _Float16* T2,
                                               _Float16* Tl, unsigned int* mask, int* bcur,
                                               float* part, float* pcnt_raw, float* lsums, int mw, int NB) {
    int b = blockIdx.x;
    int t = threadIdx.x;
    if (b < 192) {
        int which = b >> 6;
        int idx = (b & 63) * 256 + t;
        int k = idx >> 7, c = idx & 127;
        const float* S = (which == 0) ? W1 : ((which == 1) ? W2 : Wl);
        _Float16* D = (which == 0) ? T1 : ((which == 1) ? T2 : Tl);
        D[c * 128 + k] = (_Float16)S[idx];
    } else {
        int i = (b - 192) * 256 + t;
        if (i < mw) mask[i] = 0u;
        if (i < NB) bcur[i] = i * CAP;
        if (b == 192) {
            if (t < 128) part[t] = 0.f;
            else if (t == 128) pcnt_raw[0] = 0.f;
            else if (t < 131) lsums[t - 129] = 0.f;
        }
    }
}

// ---------------- bucket partition with block-local counting sort + burst copy-out ----------------

__global__ __launch_bounds__(1024) void k_partA(const int* __restrict__ ei, int* __restrict__ bcur,
                                                unsigned int* __restrict__ ebuf,
                                                const int* __restrict__ batch, unsigned int* mask,
                                                int E, int B, int NB, int NBLKE) {
    if ((int)blockIdx.x >= NBLKE) {
        int i = ((int)blockIdx.x - NBLKE) * 1024 + threadIdx.x;
        if (i < B) { int nd = batch[i]; atomicOr(&mask[nd >> 5], 1u << (nd & 31)); }
        return;
    }
    __shared__ int lcnt[NBUCK_MAX];
    __shared__ int sc[NBUCK_MAX];
    __shared__ int lcur[NBUCK_MAX];
    __shared__ int gbase[NBUCK_MAX];
    __shared__ unsigned int se[EPB];
    int tid = threadIdx.x;
    if (tid < NBUCK_MAX) lcnt[tid] = 0;
    __syncthreads();
    int base = blockIdx.x * EPB;
    unsigned int pk[8];
    int bk[8];
#pragma unroll
    for (int j = 0; j < 8; ++j) {
        int e = base + tid + j * 1024;
        if (e < E) {
            int s = ei[e], d = ei[E + e];
            pk[j] = ((unsigned int)s << 8) | (unsigned int)(d & 255);
            bk[j] = d >> 8;
            atomicAdd(&lcnt[bk[j]], 1);
        } else bk[j] = -1;
    }
    __syncthreads();
    if (tid < NBUCK_MAX) sc[tid] = lcnt[tid];
    __syncthreads();
    for (int off = 1; off < NBUCK_MAX; off <<= 1) {
        int v = 0;
        if (tid < NBUCK_MAX && tid >= off) v = sc[tid - off];
        __syncthreads();
        if (tid < NBUCK_MAX) sc[tid] += v;
        __syncthreads();
    }
    if (tid < NBUCK_MAX) {
        int cc = lcnt[tid];
        int lo = sc[tid] - cc;
        lcur[tid] = lo;
        gbase[tid] = cc ? atomicAdd(&bcur[tid], cc) : 0;
    }
    __syncthreads();
#pragma unroll
    for (int j = 0; j < 8; ++j) {
        if (bk[j] >= 0) {
            int r = atomicAdd(&lcur[bk[j]], 1);
            se[r] = pk[j];
        }
    }
    __syncthreads();
    int wid = tid >> 6, lane = tid & 63;
    for (int b = wid; b < NB; b += 16) {
        int cc = lcnt[b];
        int lo = sc[b] - cc;
        int go = gbase[b];
        for (int i = lane; i < cc; i += 64) ebuf[go + i] = se[lo + i];
    }
}

// ---------------- one-pass CSR (pad to x8), no cast ----------------

__global__ __launch_bounds__(256) void k_csr(const unsigned int* __restrict__ ebuf, const int* __restrict__ bcur,
                                             const unsigned int* __restrict__ mask,
                                             float* __restrict__ sdinv, int* __restrict__ rs,
                                             int* __restrict__ degpk, unsigned int* __restrict__ csr, int N) {
    __shared__ unsigned int se[CAP];
    __shared__ int deg[256];
    __shared__ int fde[256];
    __shared__ int sc[256];
    __shared__ int cu[256];
    __shared__ int cf[256];
    int b = blockIdx.x, t = threadIdx.x;
    deg[t] = 0; fde[t] = 0;
    __syncthreads();
    int base = b * CAP;
    int ecnt = bcur[b] - base;
    for (int i = t; i < ecnt; i += 256) {
        unsigned int v = ebuf[base + i];
        int s = v >> 8;
        int fl = (mask[s >> 5] >> (s & 31)) & 1;
        se[i] = ((unsigned int)s << 9) | ((unsigned int)fl << 8) | (v & 255);
        atomicAdd(&deg[v & 255], 1);
        if (fl) atomicAdd(&fde[v & 255], 1);
    }
    __syncthreads();
    int dv = deg[t], fv = fde[t];
    int pv = (dv + 7) & ~7;
    sc[t] = pv;
    __syncthreads();
    for (int off = 1; off < 256; off <<= 1) {
        int v2 = (t >= off) ? sc[t - off] : 0;
        __syncthreads();
        sc[t] += v2;
        __syncthreads();
    }
    int r0 = base + sc[t] - pv;
    cu[t] = r0;
    cf[t] = r0 + (dv - fv);
    int node = b * 256 + t;
    if (node < N) {
        rs[node] = r0;
        degpk[node] = dv | (fv << 16);
        float di = rsqrtf((float)(dv + 1));
        if ((mask[node >> 5] >> (node & 31)) & 1) di = -di;
        sdinv[node] = di;
    }
    __syncthreads();
    for (int i = t; i < ecnt; i += 256) {
        unsigned int v = se[i];
        int d8 = v & 255;
        int p = ((v >> 8) & 1) ? atomicAdd(&cf[d8], 1) : atomicAdd(&cu[d8], 1);
        csr[p] = v >> 9;
    }
    if (node < N) {
        for (int j = dv; j < pv; ++j) csr[r0 + j] = (unsigned int)N;
    }
}

// ---------------- cast (round-7 verified): xs = (half)(x * |dinv|), zero pad rows ----------------

__global__ __launch_bounds__(256) void k_cast(const float* __restrict__ x, const float* __restrict__ sdinv,
                                              _Float16* __restrict__ xs, _Float16* __restrict__ H, int N) {
    int i = blockIdx.x * 256 + threadIdx.x;     // each thread: 8 halves
    int nx = N * 16;
    if (i < nx) {
        int node = i >> 4;
        float da = fabsf(sdinv[node]);
        int o = i * 8;
        float4 a = *(const float4*)&x[o];
        float4 b = *(const float4*)&x[o + 4];
        h8v v;
        v[0] = (_Float16)(a.x * da); v[1] = (_Float16)(a.y * da);
        v[2] = (_Float16)(a.z * da); v[3] = (_Float16)(a.w * da);
        v[4] = (_Float16)(b.x * da); v[5] = (_Float16)(b.y * da);
        v[6] = (_Float16)(b.z * da); v[7] = (_Float16)(b.w * da);
        *(h8v*)&xs[o] = v;
    } else if (i < nx + 16) {
        *(h8v*)&xs[(size_t)i * 8] = (h8v){};                       // zero row ZN=N
    } else if (i < nx + 16 + 32) {
        int j = i - (nx + 16);
        *(h8v*)&H[(size_t)2 * N * HID + j * 8] = (h8v){};          // zero rows 2N, 2N+1
    }
}

// ---------------- fused layer 1 (round-9/11 proven): SpMM + MFMA (W1T in LDS) -> H ----------------

__global__ __launch_bounds__(256) void k_layer1(const _Float16* __restrict__ xs, const int* __restrict__ rs,
                                                const int* __restrict__ degpk, const unsigned int* __restrict__ csr,
                                                const float* __restrict__ sdinv, const _Float16* __restrict__ W1T,
                                                const float* __restrict__ bias, _Float16* __restrict__ H, int N) {
    __shared__ __align__(16) _Float16 sWT[128 * 136];
    __shared__ __align__(16) _Float16 sAgg[32 * 136];
    __shared__ float sbias[128];
    __shared__ float sda[16];
    float* sC = (float*)sWT;

    int tid = threadIdx.x;
    int wave = tid >> 6, lane = tid & 63;
    int grp = lane >> 4, rl = lane & 15;

#pragma unroll
    for (int it = 0; it < 8; ++it) {
        int lin = (it * 256 + tid) * 8;
        int c = lin >> 7, k = lin & 127;
        *(h8v*)&sWT[c * 136 + k] = *(const h8v*)&W1T[lin];
    }
    if (tid < 128) sbias[tid] = bias[tid];
    if (tid < 16) sda[tid] = fabsf(sdinv[blockIdx.x * 16 + tid]);

    int ch = rl * 8;
    int lg = wave * 4 + grp;
    int row = blockIdx.x * 16 + lg;
    bool ok = row < N;
    int p = 0, deg = 0, fd = 0;
    float sd = 0.f;
    h8v hs = {};
    if (ok) {
        p = rs[row];
        int dp = degpk[row];
        deg = dp & 0xffff; fd = dp >> 16;
        sd = sdinv[row];
        hs = *(const h8v*)&xs[(size_t)row * HID + ch];
    }
    int ud = deg - fd;
    int pd = (deg + 7) & ~7;
    int t1 = max(pd, __shfl_xor(pd, 16));
    int m  = max(t1, __shfl_xor(t1, 32));
    float U[8] = {}, F[8] = {};
    for (int i = 0; i < m; i += 16) {
        int id[16];
#pragma unroll
        for (int k = 0; k < 16; ++k) {
            int raw = (int)csr[p + i + k];
            id[k] = (i + k < pd) ? raw : N;
        }
        h8v h[16];
#pragma unroll
        for (int k = 0; k < 16; ++k) h[k] = *(const h8v*)&xs[(size_t)id[k] * HID + ch];
        h8v s0 = (h[0] + h[1]) + (h[2] + h[3]);
        h8v s1 = (h[4] + h[5]) + (h[6] + h[7]);
        h8v s2 = (h[8] + h[9]) + (h[10] + h[11]);
        h8v s3 = (h[12] + h[13]) + (h[14] + h[15]);
        h8v s  = (s0 + s1) + (s2 + s3);
#pragma unroll
        for (int j = 0; j < 8; ++j) U[j] += (float)s[j];
        if (i + 16 > ud) {
#pragma unroll
            for (int k = 0; k < 16; ++k) {
                if (i + k >= ud && i + k < deg) {
#pragma unroll
                    for (int j = 0; j < 8; ++j) F[j] += (float)h[k][j];
                }
            }
        }
    }
    {
        float da = fabsf(sd);
        float keep = (sd < 0.f) ? 0.f : 1.f;
        h8v lo = {}, hi = {};
        if (ok) {
#pragma unroll
            for (int j = 0; j < 8; ++j) {
                float f = (float)hs[j];
                lo[j] = (_Float16)(da * (U[j] + f));
                hi[j] = (_Float16)(da * (U[j] - F[j] + keep * f));
            }
        }
        *(h8v*)&sAgg[(2 * lg) * 136 + ch] = lo;
        *(h8v*)&sAgg[(2 * lg + 1) * 136 + ch] = hi;
    }
    __syncthreads();

    int g = lane >> 4;
    int rowtile = (wave & 1) * 16;
    int colbase = (wave >> 1) * 64;
    f4v acc[4];
#pragma unroll
    for (int cc = 0; cc < 4; ++cc) acc[cc] = (f4v){0.f, 0.f, 0.f, 0.f};
#pragma unroll
    for (int kb = 0; kb < 4; ++kb) {
        int k0 = kb * 32 + g * 8;
        h8v av = *(const h8v*)&sAgg[(rowtile + rl) * 136 + k0];
#pragma unroll
        for (int cc = 0; cc < 4; ++cc) {
            h8v bv = *(const h8v*)&sWT[(colbase + cc * 16 + rl) * 136 + k0];
            acc[cc] = __builtin_amdgcn_mfma_f32_16x16x32_f16(bv, av, acc[cc], 0, 0, 0);
        }
    }
    __syncthreads();   // sWT reads done; overlay as sC

    int lrow = rowtile + rl;
    float dsc = sda[lrow >> 1];
#pragma unroll
    for (int cc = 0; cc < 4; ++cc) {
        f4v v = acc[cc];
        int col = colbase + cc * 16 + g * 4;
#pragma unroll
        for (int i2 = 0; i2 < 4; ++i2) v[i2] = fmaxf(v[i2] + sbias[col + i2], 0.f) * dsc;
        *(f4v*)&sC[lrow * 132 + col] = v;
    }
    __syncthreads();

    int sr = tid >> 3, ck = tid & 7;
    int gRow = blockIdx.x * 32 + sr;
    if (gRow < 2 * N) {
        const float* src = &sC[sr * 132 + ck * 16];
        h8v o0, o1;
#pragma unroll
        for (int j = 0; j < 8; ++j) { o0[j] = (_Float16)src[j]; o1[j] = (_Float16)src[8 + j]; }
        _Float16* dst = &H[(size_t)gRow * HID + ck * 16];
        *(h8v*)&dst[0] = o0;
        *(h8v*)&dst[8] = o1;
    }
}

// ---------------- fused layer 2: batch SpMM + MFMA (W2T in LDS) -> gf/env, + fused pos-sum ----------------

__global__ __launch_bounds__(256) void k_layer2(const _Float16* __restrict__ H, const int* __restrict__ rs,
                                                const int* __restrict__ degpk, const unsigned int* __restrict__ csr,
                                                const float* __restrict__ sdinv, const int* __restrict__ batch,
                                                const int* __restrict__ labels,
                                                const _Float16* __restrict__ W2T, const float* __restrict__ bias,
                                                float* __restrict__ gf, _Float16* __restrict__ envh,
                                                float* __restrict__ yv, float* __restrict__ part,
                                                float* __restrict__ pcnt_raw, int B, int N) {
    __shared__ __align__(16) _Float16 sWT[128 * 136];
    __shared__ __align__(16) _Float16 sAgg[32 * 136];
    __shared__ float sbias[128];
    __shared__ float sy2[16];
    float* sC = (float*)sWT;

    int tid = threadIdx.x;
    int wave = tid >> 6, lane = tid & 63;
    int grp = lane >> 4, rl = lane & 15;

#pragma unroll
    for (int it = 0; it < 8; ++it) {
        int lin = (it * 256 + tid) * 8;
        int c = lin >> 7, k = lin & 127;
        *(h8v*)&sWT[c * 136 + k] = *(const h8v*)&W2T[lin];
    }
    if (tid < 128) sbias[tid] = bias[tid];

    int ch = rl * 8;
    int lg = wave * 4 + grp;
    int ri = blockIdx.x * 16 + lg;
    bool ok = ri < B;
    int p = 0, deg = 0, row = 0;
    float da = 0.f;
    h8v hn = {}, he = {};
    if (ok) {
        row = batch[ri];
        p = rs[row];
        deg = degpk[row] & 0xffff;
        da = fabsf(sdinv[row]);
        hn = *(const h8v*)&H[(size_t)row * 256 + ch];
        he = *(const h8v*)&H[(size_t)row * 256 + 128 + ch];
    }
    int pd = (deg + 7) & ~7;
    int t1 = max(pd, __shfl_xor(pd, 16));
    int m  = max(t1, __shfl_xor(t1, 32));
    float a[8] = {}, e[8] = {};
    for (int i = 0; i < m; i += 8) {
        int id[8];
#pragma unroll
        for (int k = 0; k < 8; ++k) {
            int raw = (int)csr[p + i + k];
            id[k] = (i + k < pd) ? raw : N;
        }
        h8v xn[8], xe[8];
#pragma unroll
        for (int k = 0; k < 8; ++k) {
            xn[k] = *(const h8v*)&H[(size_t)id[k] * 256 + ch];
            xe[k] = *(const h8v*)&H[(size_t)id[k] * 256 + 128 + ch];
        }
        h8v sn = ((xn[0] + xn[1]) + (xn[2] + xn[3])) + ((xn[4] + xn[5]) + (xn[6] + xn[7]));
        h8v sv = ((xe[0] + xe[1]) + (xe[2] + xe[3])) + ((xe[4] + xe[5]) + (xe[6] + xe[7]));
#pragma unroll
        for (int j = 0; j < 8; ++j) { a[j] += (float)sn[j]; e[j] += (float)sv[j]; }
    }
    {
        h8v lo = {}, hi = {};
        if (ok) {
#pragma unroll
            for (int j = 0; j < 8; ++j) {
                lo[j] = (_Float16)(da * (a[j] + (float)hn[j]));
                hi[j] = (_Float16)(da * (e[j] + (float)he[j]));
            }
        }
        *(h8v*)&sAgg[(2 * lg) * 136 + ch] = lo;
        *(h8v*)&sAgg[(2 * lg + 1) * 136 + ch] = hi;
    }
    __syncthreads();

    int g = lane >> 4;
    int rowtile = (wave & 1) * 16;
    int colbase = (wave >> 1) * 64;
    f4v acc[4];
#pragma unroll
    for (int cc = 0; cc < 4; ++cc) acc[cc] = (f4v){0.f, 0.f, 0.f, 0.f};
#pragma unroll
    for (int kb = 0; kb < 4; ++kb) {
        int k0 = kb * 32 + g * 8;
        h8v av = *(const h8v*)&sAgg[(rowtile + rl) * 136 + k0];
#pragma unroll
        for (int cc = 0; cc < 4; ++cc) {
            h8v bv = *(const h8v*)&sWT[(colbase + cc * 16 + rl) * 136 + k0];
            acc[cc] = __builtin_amdgcn_mfma_f32_16x16x32_f16(bv, av, acc[cc], 0, 0, 0);
        }
    }
    __syncthreads();

    int lrow = rowtile + rl;
#pragma unroll
    for (int cc = 0; cc < 4; ++cc) {
        f4v v = acc[cc];
        int col = colbase + cc * 16 + g * 4;
#pragma unroll
        for (int i2 = 0; i2 < 4; ++i2) v[i2] = fmaxf(v[i2] + sbias[col + i2], 0.f);
        *(f4v*)&sC[lrow * 132 + col] = v;
    }
    __syncthreads();

    int sr = tid >> 3, ck = tid & 7;
    int ri2 = blockIdx.x * 16 + (sr >> 1);
    if (ri2 < B) {
        const float* src = &sC[sr * 132 + ck * 16];
        if ((sr & 1) == 0) {
            float* dst = &gf[(size_t)ri2 * HID + ck * 16];
#pragma unroll
            for (int q = 0; q < 4; ++q) *(float4*)&dst[q * 4] = *(const float4*)&src[q * 4];
        } else {
            h8v o0, o1;
#pragma unroll
            for (int j = 0; j < 8; ++j) { o0[j] = (_Float16)src[j]; o1[j] = (_Float16)src[8 + j]; }
            _Float16* dst = &envh[(size_t)ri2 * HID + ck * 16];
            *(h8v*)&dst[0] = o0;
            *(h8v*)&dst[8] = o1;
        }
    }

    // ---- fused pos-sum: part[col] += sum_r y_r * gf_r[col]; pcnt += sum y; write yv ----
    int rr = blockIdx.x * 16 + tid;
    if (tid < 16) {
        float y = 0.f;
        if (rr < B) {
            y = (labels[batch[rr]] == 1) ? 1.f : 0.f;
            yv[rr] = y;
        }
        sy2[tid] = y;
    }
    __syncthreads();
    if (tid < 128) {
        float acc2 = 0.f;
#pragma unroll
        for (int r2 = 0; r2 < 16; ++r2) acc2 += sy2[r2] * sC[(2 * r2) * 132 + tid];
        atomicAdd(&part[tid], acc2);
    } else if (tid == 128) {
        float ps = 0.f;
#pragma unroll
        for (int r2 = 0; r2 < 16; ++r2) ps += sy2[r2];
        atomicAdd(&pcnt_raw[0], ps);
    }
}

// ---------------- ctxvec: v = Wctx @ (pos_sum / pos_cnt) ----------------

__global__ __launch_bounds__(128) void k_ctxvec(const float* __restrict__ Wctx, const float* __restrict__ part,
                                                const float* __restrict__ pcnt_raw, float* v) {
    __shared__ float sproto[128];
    int t = threadIdx.x;
    float pc = pcnt_raw[0];
    sproto[t] = part[t] / pc;
    __syncthreads();
    float acc = 0.f;
#pragma unroll 4
    for (int j = 0; j < 128; ++j) acc += Wctx[t * 128 + j] * sproto[j];
    v[t] = acc;
}

// ---------------- fused heads: T = env@Wloc (MFMA, in-register) + bilinear dots + loss partials ----------------
// 64 batch rows per block; lane (wave,rl,g): T row blk*64+wave*16+rl, cols {cf*16+g*4..+3}

__global__ __launch_bounds__(256) void k_headsT(const _Float16* __restrict__ envh, const float* __restrict__ gf,
                                                const _Float16* __restrict__ WlT, const float* __restrict__ v,
                                                const float* __restrict__ yv, const float* __restrict__ bctx,
                                                const float* __restrict__ bloc, float* __restrict__ lsums, int B) {
    __shared__ __align__(16) _Float16 sWT[128 * 136];
    __shared__ float sv[128];
    int tid = threadIdx.x;
#pragma unroll
    for (int it = 0; it < 8; ++it) {
        int lin = (it * 256 + tid) * 8;
        int c = lin >> 7, k = lin & 127;
        *(h8v*)&sWT[c * 136 + k] = *(const h8v*)&WlT[lin];
    }
    if (tid < 128) sv[tid] = v[tid];
    __syncthreads();

    int wave = tid >> 6, lane = tid & 63;
    int rl = lane & 15, g = lane >> 4;
    int r = blockIdx.x * 64 + wave * 16 + rl;
    bool rok = r < B;
    f4v acc[8];
#pragma unroll
    for (int cf = 0; cf < 8; ++cf) acc[cf] = (f4v){0.f, 0.f, 0.f, 0.f};
#pragma unroll
    for (int kb = 0; kb < 4; ++kb) {
        int k0 = kb * 32 + g * 8;
        h8v av = {};
        if (rok) av = *(const h8v*)&envh[(size_t)r * HID + k0];
#pragma unroll
        for (int cf = 0; cf < 8; ++cf) {
            h8v bv = *(const h8v*)&sWT[(cf * 16 + rl) * 136 + k0];
            acc[cf] = __builtin_amdgcn_mfma_f32_16x16x32_f16(bv, av, acc[cf], 0, 0, 0);
        }
    }
    // per-lane dots over its 32 columns
    float s1 = 0.f, s2 = 0.f;
    if (rok) {
#pragma unroll
        for (int cf = 0; cf < 8; ++cf) {
            int col = cf * 16 + g * 4;
            float4 gv = *(const float4*)&gf[(size_t)r * HID + col];
            s2 += acc[cf][0] * gv.x + acc[cf][1] * gv.y + acc[cf][2] * gv.z + acc[cf][3] * gv.w;
            s1 += sv[col] * gv.x + sv[col + 1] * gv.y + sv[col + 2] * gv.z + sv[col + 3] * gv.w;
        }
    }
    // reduce across g (lanes rl, rl+16, rl+32, rl+48)
    s1 += __shfl_xor(s1, 16); s1 += __shfl_xor(s1, 32);
    s2 += __shfl_xor(s2, 16); s2 += __shfl_xor(s2, 32);
    float l1 = 0.f, l2 = 0.f;
    if (g == 0 && rok) {
        float y = yv[r];
        float z1 = s1 + bctx[0];
        float z2 = s2 + bloc[0];
        l1 = fmaxf(z1, 0.f) + log1pf(expf(-fabsf(z1))) - z1 * y;
        l2 = fmaxf(z2, 0.f) + log1pf(expf(-fabsf(z2))) - z2 * (1.f - y);
    }
#pragma unroll
    for (int o = 1; o < 64; o <<= 1) {
        l1 += __shfl_xor(l1, o);
        l2 += __shfl_xor(l2, o);
    }
    if (lane == 0) {
        atomicAdd(&lsums[0], l1);
        atomicAdd(&lsums[1], l2);
    }
}

__global__ void k_final(const float* __restrict__ lsums, const float* __restrict__ pcnt_raw,
                        float* out_loss, int B) {
    if (blockIdx.x == 0 && threadIdx.x == 0) {
        float pc = pcnt_raw[0];
        float nc = (float)B - pc;
        float total = 0.5f * (lsums[0] / (float)B) + 0.5f * (lsums[1] / (float)B);
        out_loss[0] = (pc > 0.f && nc > 0.f) ? total : 0.f;
    }
}

// ---------------- launcher ----------------

extern "C" void kernel_launch(void* const* d_in, const int* in_sizes, int n_in,
                              void* d_out, int out_size, void* d_ws, size_t ws_size,
                              hipStream_t stream) {
    const float* x      = (const float*)d_in[0];
    const int*   ei     = (const int*)d_in[1];
    const int*   batch  = (const int*)d_in[2];
    const int*   labels = (const int*)d_in[3];
    const float* W1     = (const float*)d_in[4];
    const float* b1     = (const float*)d_in[5];
    const float* W2     = (const float*)d_in[6];
    const float* b2     = (const float*)d_in[7];
    const float* Wctx   = (const float*)d_in[8];
    const float* bctx   = (const float*)d_in[9];
    const float* Wloc   = (const float*)d_in[10];
    const float* bloc   = (const float*)d_in[11];

    int N = in_sizes[0] / HID;
    int E = in_sizes[1] / 2;
    int B = in_sizes[2];
    float* out = (float*)d_out;

    char* wsb = (char*)d_ws;
    size_t off = 0;
    auto alloc = [&](size_t bytes) -> char* {
        char* p = wsb + off;
        off += (bytes + 255) & ~(size_t)255;
        return p;
    };
    int NB = ceil_div(N, 256);
    int mw = ceil_div(N, 32);

    _Float16* xs   = (_Float16*)alloc((size_t)(N + 1) * HID * 2);
    _Float16* H    = (_Float16*)alloc((size_t)(2 * N + 2) * HID * 2);
    unsigned int* ebuf = (unsigned int*)alloc((size_t)NB * CAP * 4);
    unsigned int* csr  = (unsigned int*)alloc((size_t)NB * CAP * 4);
    float* sdinv = (float*)alloc((size_t)N * 4);
    int*   rs    = (int*)alloc((size_t)N * 4);
    int*   degpk = (int*)alloc((size_t)N * 4);
    int*   bcur  = (int*)alloc((size_t)NB * 4);
    unsigned int* mask = (unsigned int*)alloc((size_t)mw * 4);
    _Float16* W1T = (_Float16*)alloc(128 * 128 * 2);
    _Float16* W2T = (_Float16*)alloc(128 * 128 * 2);
    _Float16* WlT = (_Float16*)alloc(128 * 128 * 2);
    _Float16* envh  = (_Float16*)alloc((size_t)B * HID * 2);
    float* yv    = (float*)alloc((size_t)B * 4);
    float* part  = (float*)alloc(128 * 4);
    float* pcnt_raw = (float*)alloc(256);
    float* lsums = (float*)alloc(256);
    float* vvec  = (float*)alloc(128 * 4);
    (void)ws_size; (void)n_in; (void)out_size;

    int NBLKE = ceil_div(E, EPB);
    int NBLKB = ceil_div(B, 1024);

    k_setup<<<192 + ceil_div(mw, 256), 256, 0, stream>>>(W1, W2, Wloc, W1T, W2T, WlT, mask, bcur,
                                                         part, pcnt_raw, lsums, mw, NB);
    k_partA<<<NBLKE + NBLKB, 1024, 0, stream>>>(ei, bcur, ebuf, batch, mask, E, B, NB, NBLKE);
    k_csr<<<NB, 256, 0, stream>>>(ebuf, bcur, mask, sdinv, rs, degpk, csr, N);
    k_cast<<<ceil_div(N * 16 + 48, 256), 256, 0, stream>>>(x, sdinv, xs, H, N);

    // fused layer 1
    k_layer1<<<ceil_div(N, 16), 256, 0, stream>>>(xs, rs, degpk, csr, sdinv, W1T, b1, H, N);

    // fused layer 2 (+ pos-sum partials + yv)
    k_layer2<<<ceil_div(B, 16), 256, 0, stream>>>(H, rs, degpk, csr, sdinv, batch, labels, W2T, b2,
                                                  out, envh, yv, part, pcnt_raw, B, N);

    // heads
    k_ctxvec<<<1, 128, 0, stream>>>(Wctx, part, pcnt_raw, vvec);
    k_headsT<<<ceil_div(B, 64), 256, 0, stream>>>(envh, out, WlT, vvec, yv, bctx, bloc, lsums, B);
    k_final<<<1, 1, 0, stream>>>(lsums, pcnt_raw, out + (size_t)B * HID, B);
}